// Round 4
// baseline (9424.673 us; speedup 1.0000x reference)
//
#include <hip/hip_runtime.h>
#include <hip/hip_bf16.h>
#include <hip/hip_fp16.h>

#define B 256
#define L 128
#define F 256
#define S 512
#define G4 1024  // 4*F gate rows

typedef _Float16 h2raw __attribute__((ext_vector_type(2)));

__device__ __forceinline__ float fdot2u(unsigned a, unsigned b, float c) {
#if __has_builtin(__builtin_amdgcn_fdot2)
    return __builtin_amdgcn_fdot2(__builtin_bit_cast(h2raw, a), __builtin_bit_cast(h2raw, b), c, false);
#else
    __half2 ah = __builtin_bit_cast(__half2, a), bh = __builtin_bit_cast(__half2, b);
    float2 af = __half22float2(ah), bf = __half22float2(bh);
    return c + af.x * bf.x + af.y * bf.y;
#endif
}

// fast device transcendentals: v_exp_f32 / v_rcp_f32 based
__device__ __forceinline__ float fast_rcp(float x) { return __builtin_amdgcn_rcpf(x); }
__device__ __forceinline__ float sigf(float x) {
    float e = __expf(-x);
    return fast_rcp(1.0f + e);
}
__device__ __forceinline__ float tanhf_fast(float x) {
    x = fminf(fmaxf(x, -15.0f), 15.0f);
    float e = __expf(-2.0f * x);
    return (1.0f - e) * fast_rcp(1.0f + e);
}

template <int CTRL>
__device__ __forceinline__ float dpp_add(float x) {
    int v = __builtin_amdgcn_update_dpp(0, __builtin_bit_cast(int, x), CTRL, 0xF, 0xF, true);
    return x + __builtin_bit_cast(float, v);
}

// Read one weight dword back from its AGPR. volatile: must re-read every
// iteration (CSE across iterations would recreate the VGPR-pressure problem).
#define AREAD(x) ({ unsigned r_; asm volatile("v_accvgpr_read_b32 %0, %1" : "=v"(r_) : "a"(x)); r_; })

// Prep: pack combined W = W_ih + W_hh into the main kernel's register-load layout.
// Wpk[m][tid] (16B each, m<32, tid<1024): for thread tid (j=tid>>2, q=tid&3), load m
// (g=m>>3, kk8=m&7) holds 4 half2 = k-pairs kp0..kp0+3 of row r=g*256+j, kp0=q*32+kk8*4.
__global__ void prep_kernel(const float* __restrict__ Wih,
                            const float* __restrict__ Whh,
                            const float* __restrict__ bih,
                            const float* __restrict__ bhh,
                            uint4* __restrict__ Wpk, float* __restrict__ bias_sum) {
    int e = blockIdx.x * blockDim.x + threadIdx.x;  // 32768 elements
    if (e < G4) bias_sum[e] = bih[e] + bhh[e];
    int m = e >> 10, tid = e & 1023;
    int j = tid >> 2, q = tid & 3;
    int g = m >> 3, kk8 = m & 7;
    int r = g * F + j;
    int kp0 = q * 32 + kk8 * 4;
    unsigned pk[4];
    #pragma unroll
    for (int i = 0; i < 4; ++i) {
        int k = 2 * (kp0 + i);
        float w0 = Wih[r * F + k]     + Whh[r * F + k];
        float w1 = Wih[r * F + k + 1] + Whh[r * F + k + 1];
        pk[i] = __builtin_bit_cast(unsigned, __floats2half2_rn(w0, w1));
    }
    Wpk[(size_t)m * 1024 + tid] = make_uint4(pk[0], pk[1], pk[2], pk[3]);
}

// init = elu(x[0] @ Wi.T + bi) -> h0, c0 (fp32 in workspace)
__global__ void init_kernel(const float* __restrict__ x,
                            const float* __restrict__ Wi,
                            const float* __restrict__ bi,
                            float* __restrict__ h, float* __restrict__ c) {
    __shared__ float xs[L];
    int b = blockIdx.x, j = threadIdx.x;
    if (j < L) xs[j] = x[b * L + j];
    __syncthreads();
    float acc = bi[j];
    for (int k = 0; k < L; ++k) acc += xs[k] * Wi[j * L + k];
    float v = acc > 0.0f ? acc : expm1f(acc);
    h[b * F + j] = v;
    c[b * F + j] = v;
}

// Step 0: gates = last_feat @ W_ih.T + h0 @ W_hh.T + bias ; writes outs[0], updates h,c
__global__ void step0_kernel(const float* __restrict__ lf,
                             const float* __restrict__ Wih,
                             const float* __restrict__ Whh,
                             const float* __restrict__ bias_sum,
                             float* __restrict__ h, float* __restrict__ c,
                             float* __restrict__ out) {
    __shared__ float inp[F];
    __shared__ float h0[F];
    int b = blockIdx.x, j = threadIdx.x;
    inp[j] = lf[b * F + j];
    h0[j] = h[b * F + j];
    __syncthreads();
    float a0 = bias_sum[0 * F + j];
    float a1 = bias_sum[1 * F + j];
    float a2 = bias_sum[2 * F + j];
    float a3 = bias_sum[3 * F + j];
    for (int k = 0; k < F; ++k) {
        float ik = inp[k], hk = h0[k];
        a0 += ik * Wih[(0 * F + j) * F + k] + hk * Whh[(0 * F + j) * F + k];
        a1 += ik * Wih[(1 * F + j) * F + k] + hk * Whh[(1 * F + j) * F + k];
        a2 += ik * Wih[(2 * F + j) * F + k] + hk * Whh[(2 * F + j) * F + k];
        a3 += ik * Wih[(3 * F + j) * F + k] + hk * Whh[(3 * F + j) * F + k];
    }
    float c0v = c[b * F + j];
    float c1v = sigf(a1) * c0v + sigf(a0) * tanhf_fast(a2);
    float h1v = sigf(a3) * tanhf_fast(c1v);
    h[b * F + j] = h1v;
    c[b * F + j] = c1v;
    out[(size_t)b * F + j] = h1v;  // t=0 row
}

// Main recurrence, weight-stationary in AGPRs (pinned via inline asm).
// One block per batch element. 1024 threads: j = tid>>2 (hidden unit),
// q = tid&3 (k-quarter, reduced via DPP quad_perm).
// hbuf is swizzled in 16B chunks: slice q, chunk k8 -> slot q*8 + ((k8+2q)&7),
// so the 4 q-slices hit disjoint bank quads (conflict-free broadcast reads).
__launch_bounds__(1024, 1)
__global__ void lstm_main(const uint4* __restrict__ Wpk,
                          const float* __restrict__ bias_sum,
                          const float* __restrict__ h_in,
                          const float* __restrict__ c_in,
                          float* __restrict__ out) {
    int b = blockIdx.x;
    int tid = threadIdx.x;
    int j = tid >> 2;
    int q = tid & 3;

    __shared__ uint4 hbuf[2][32];  // 2 x 512B, double-buffered hidden state (f16, swizzled)

    // One-time: weights into AGPRs (128 per thread), coalesced loads.
    unsigned aw[128];
    #pragma unroll
    for (int m = 0; m < 32; ++m) {
        uint4 v = Wpk[(size_t)m * 1024 + tid];
        asm volatile("v_accvgpr_write_b32 %0, %1" : "=a"(aw[4 * m + 0]) : "v"(v.x));
        asm volatile("v_accvgpr_write_b32 %0, %1" : "=a"(aw[4 * m + 1]) : "v"(v.y));
        asm volatile("v_accvgpr_write_b32 %0, %1" : "=a"(aw[4 * m + 2]) : "v"(v.z));
        asm volatile("v_accvgpr_write_b32 %0, %1" : "=a"(aw[4 * m + 3]) : "v"(v.w));
    }

    float bias[4];
    #pragma unroll
    for (int g = 0; g < 4; ++g) bias[g] = bias_sum[g * F + j];
    float cj = c_in[b * F + j];

    // loop-invariant swizzled read slots (8 chunks of my q-slice)
    int slot[8];
    #pragma unroll
    for (int i = 0; i < 8; ++i) slot[i] = q * 8 + ((i + 2 * q) & 7);
    // loop-invariant swizzled write position (half index) for hidden unit j
    const int wqs = j >> 6, wk8 = (j >> 3) & 7;
    const int wpos = (wqs * 8 + ((wk8 + 2 * wqs) & 7)) * 8 + (j & 7);

    if (tid < F) {
        int jj = tid, qs = jj >> 6, k8 = (jj >> 3) & 7;
        int sl = qs * 8 + ((k8 + 2 * qs) & 7);
        ((__half*)hbuf[0])[sl * 8 + (jj & 7)] = __float2half(h_in[b * F + jj]);
    }
    __syncthreads();

    int cur = 0;
    for (int t = 1; t < S; ++t) {
        // my 64-half k-slice of h: 8 x 16B, conflict-free (swizzled slots)
        uint4 hr[8];
        #pragma unroll
        for (int i = 0; i < 8; ++i) hr[i] = hbuf[cur][slot[i]];

        float a[4];
        #pragma unroll
        for (int g = 0; g < 4; ++g) {
            float acc = 0.0f;
            #pragma unroll
            for (int i = 0; i < 8; ++i) {
                uint4 hv = hr[i];
                const int base = (g * 8 + i) * 4;
                acc = fdot2u(AREAD(aw[base + 0]), hv.x, acc);
                acc = fdot2u(AREAD(aw[base + 1]), hv.y, acc);
                acc = fdot2u(AREAD(aw[base + 2]), hv.z, acc);
                acc = fdot2u(AREAD(aw[base + 3]), hv.w, acc);
            }
            a[g] = acc;
        }
        // quad butterfly: sum the 4 k-quarters; all lanes get the full sums
        #pragma unroll
        for (int g = 0; g < 4; ++g) {
            a[g] = dpp_add<0xB1>(a[g]);  // quad_perm [1,0,3,2]: xor 1
            a[g] = dpp_add<0x4E>(a[g]);  // quad_perm [2,3,0,1]: xor 2
            a[g] += bias[g];
        }
        float c2 = sigf(a[1]) * cj + sigf(a[0]) * tanhf_fast(a[2]);
        float h2 = sigf(a[3]) * tanhf_fast(c2);
        cj = c2;
        if (q == 0) {
            ((__half*)hbuf[cur ^ 1])[wpos] = __float2half(h2);
            __builtin_nontemporal_store(h2, &out[((size_t)t * B + b) * F + j]);
        }
        __syncthreads();
        cur ^= 1;
    }
}

extern "C" void kernel_launch(void* const* d_in, const int* in_sizes, int n_in,
                              void* d_out, int out_size, void* d_ws, size_t ws_size,
                              hipStream_t stream) {
    const float* x   = (const float*)d_in[0];
    const float* lf  = (const float*)d_in[1];
    const float* Wi  = (const float*)d_in[2];
    const float* bi  = (const float*)d_in[3];
    const float* Wih = (const float*)d_in[4];
    const float* Whh = (const float*)d_in[5];
    const float* bih = (const float*)d_in[6];
    const float* bhh = (const float*)d_in[7];
    // d_in[8], d_in[9] (Wo, bo): computed-and-discarded in the reference; unused.
    float* out = (float*)d_out;

    float* ws    = (float*)d_ws;
    float* h     = ws;               // 65536 floats
    float* c     = ws + 65536;       // 65536 floats
    float* bias  = ws + 131072;      // 1024 floats
    uint4* Wpk   = (uint4*)(ws + 132096);  // 32768 x 16B = 512 KB

    prep_kernel<<<128, 256, 0, stream>>>(Wih, Whh, bih, bhh, Wpk, bias);
    init_kernel<<<B, F, 0, stream>>>(x, Wi, bi, h, c);
    step0_kernel<<<B, F, 0, stream>>>(lf, Wih, Whh, bias, h, c, out);
    lstm_main<<<B, 1024, 0, stream>>>(Wpk, bias, h, c, out);
}

// Round 5
// 915.807 us; speedup vs baseline: 10.2911x; 10.2911x over previous
//
#include <hip/hip_runtime.h>
#include <hip/hip_bf16.h>
#include <hip/hip_fp16.h>

#define B 256
#define L 128
#define F 256
#define S 512
#define G4 1024  // 4*F gate rows

typedef _Float16 h2raw __attribute__((ext_vector_type(2)));

__device__ __forceinline__ float fdot2u(unsigned a, unsigned b, float c) {
#if __has_builtin(__builtin_amdgcn_fdot2)
    return __builtin_amdgcn_fdot2(__builtin_bit_cast(h2raw, a), __builtin_bit_cast(h2raw, b), c, false);
#else
    __half2 ah = __builtin_bit_cast(__half2, a), bh = __builtin_bit_cast(__half2, b);
    float2 af = __half22float2(ah), bf = __half22float2(bh);
    return c + af.x * bf.x + af.y * bf.y;
#endif
}

// fast device transcendentals: v_exp_f32 / v_rcp_f32 based
__device__ __forceinline__ float fast_rcp(float x) { return __builtin_amdgcn_rcpf(x); }
__device__ __forceinline__ float sigf(float x) {
    float e = __expf(-x);
    return fast_rcp(1.0f + e);
}
__device__ __forceinline__ float tanhf_fast(float x) {
    x = fminf(fmaxf(x, -15.0f), 15.0f);
    float e = __expf(-2.0f * x);
    return (1.0f - e) * fast_rcp(1.0f + e);
}

template <int CTRL>
__device__ __forceinline__ float dpp_add(float x) {
    int v = __builtin_amdgcn_update_dpp(0, __builtin_bit_cast(int, x), CTRL, 0xF, 0xF, true);
    return x + __builtin_bit_cast(float, v);
}

// Prep: pack combined W = W_ih + W_hh for the 512-thread main kernel.
// Thread tid: j = tid>>1 (hidden unit), q = tid&1 (k-half).
// Chunk n in [0,64): n<48 -> register gates g=n>>4 (i,f,g), m=n&15;
//                    n>=48 -> LDS gate g=3 (o), m=n-48.
// Wpk[n*512+tid] = 4 half2 = k-pairs kp = q*64 + m*4 + {0..3} of row g*256+j.
__global__ void prep_kernel(const float* __restrict__ Wih,
                            const float* __restrict__ Whh,
                            const float* __restrict__ bih,
                            const float* __restrict__ bhh,
                            uint4* __restrict__ Wpk, float* __restrict__ bias_sum) {
    int e = blockIdx.x * blockDim.x + threadIdx.x;  // 32768 elements
    if (e < G4) bias_sum[e] = bih[e] + bhh[e];
    int n = e >> 9, tid = e & 511;
    int j = tid >> 1, q = tid & 1;
    int g = (n < 48) ? (n >> 4) : 3;
    int m = (n < 48) ? (n & 15) : (n - 48);
    int r = g * F + j;
    int kp0 = q * 64 + m * 4;
    unsigned pk[4];
    #pragma unroll
    for (int i = 0; i < 4; ++i) {
        int k = 2 * (kp0 + i);
        float w0 = Wih[(size_t)r * F + k]     + Whh[(size_t)r * F + k];
        float w1 = Wih[(size_t)r * F + k + 1] + Whh[(size_t)r * F + k + 1];
        pk[i] = __builtin_bit_cast(unsigned, __floats2half2_rn(w0, w1));
    }
    Wpk[(size_t)n * 512 + tid] = make_uint4(pk[0], pk[1], pk[2], pk[3]);
}

// init = elu(x[0] @ Wi.T + bi) -> h0, c0 (fp32 in workspace), float4 loads
__global__ void init_kernel(const float* __restrict__ x,
                            const float* __restrict__ Wi,
                            const float* __restrict__ bi,
                            float* __restrict__ h, float* __restrict__ c) {
    __shared__ float4 xs4[L / 4];
    int b = blockIdx.x, j = threadIdx.x;
    if (j < L / 4) xs4[j] = ((const float4*)(x + (size_t)b * L))[j];
    __syncthreads();
    float acc = bi[j];
    const float4* wp = (const float4*)(Wi + (size_t)j * L);
    #pragma unroll 8
    for (int k = 0; k < L / 4; ++k) {
        float4 w = wp[k], xv = xs4[k];
        acc += w.x * xv.x + w.y * xv.y + w.z * xv.z + w.w * xv.w;
    }
    float v = acc > 0.0f ? acc : expm1f(acc);
    h[b * F + j] = v;
    c[b * F + j] = v;
}

// Step 0: gates = last_feat @ W_ih.T + h0 @ W_hh.T + bias.
// 1024 threads: j = tid&255, q = tid>>8 picks a 128-wide slice of the
// concatenated K=512 ([inp;h0]) dimension. float4 loads, LDS partial reduce.
__global__ void step0_kernel(const float* __restrict__ lf,
                             const float* __restrict__ Wih,
                             const float* __restrict__ Whh,
                             const float* __restrict__ bias_sum,
                             float* __restrict__ h, float* __restrict__ c,
                             float* __restrict__ out) {
    __shared__ float vecs[2 * F];            // [inp(256) ; h0(256)]
    __shared__ float partial[3][4][F];
    int b = blockIdx.x, tid = threadIdx.x;
    int j = tid & (F - 1), q = tid >> 8;
    if (q == 0) vecs[j] = lf[(size_t)b * F + j];
    else if (q == 1) vecs[F + j] = h[(size_t)b * F + j];
    __syncthreads();
    const float* mat = (q < 2) ? Wih : Whh;
    int ks = (q & 1) * 128;
    const float4* vp = (const float4*)(&vecs[(q >> 1) * F + ks]);
    float a[4] = {0.f, 0.f, 0.f, 0.f};
    #pragma unroll
    for (int g = 0; g < 4; ++g) {
        const float4* wp = (const float4*)(&mat[(size_t)(g * F + j) * F + ks]);
        float acc = 0.f;
        #pragma unroll 8
        for (int i = 0; i < 32; ++i) {
            float4 w = wp[i], v = vp[i];
            acc += w.x * v.x + w.y * v.y + w.z * v.z + w.w * v.w;
        }
        a[g] = acc;
    }
    if (q > 0) {
        #pragma unroll
        for (int g = 0; g < 4; ++g) partial[q - 1][g][j] = a[g];
    }
    __syncthreads();
    if (q == 0) {
        #pragma unroll
        for (int g = 0; g < 4; ++g) {
            for (int p = 0; p < 3; ++p) a[g] += partial[p][g][j];
            a[g] += bias_sum[g * F + j];
        }
        float c0v = c[(size_t)b * F + j];
        float c1v = sigf(a[1]) * c0v + sigf(a[0]) * tanhf_fast(a[2]);
        float h1v = sigf(a[3]) * tanhf_fast(c1v);
        h[(size_t)b * F + j] = h1v;
        c[(size_t)b * F + j] = c1v;
        out[(size_t)b * F + j] = h1v;  // t=0 row
    }
}

// Main recurrence. One block of 512 threads per batch element.
// j = tid>>1 (hidden unit), q = tid&1 (k-half, reduced via DPP xor-1).
// Weights: gates i,f,g register-resident (192 dwords/thread, 384 KB/CU);
// gate o LDS-resident (128 KB/CU). Budget: 192 + ~45 working <= 256
// (launch_bounds(512,2) -> 2 waves/SIMD -> 256 regs/thread).
__launch_bounds__(512, 2)
__global__ void lstm_main(const uint4* __restrict__ Wpk,
                          const float* __restrict__ bias_sum,
                          const float* __restrict__ h_in,
                          const float* __restrict__ c_in,
                          float* __restrict__ out) {
    int b = blockIdx.x;
    int tid = threadIdx.x;
    int j = tid >> 1;
    int q = tid & 1;

    __shared__ uint4 lds_wo[16][512];   // gate-o weights, 128 KB
    __shared__ uint4 hbuf[2][F / 8];    // 2 x 512 B hidden state (f16)

    // One-time: gates i,f,g into registers (coalesced), gate o into LDS.
    uint4 wr[48];
    #pragma unroll
    for (int n = 0; n < 48; ++n) wr[n] = Wpk[(size_t)n * 512 + tid];
    #pragma unroll
    for (int m = 0; m < 16; ++m) lds_wo[m][tid] = Wpk[(size_t)(48 + m) * 512 + tid];

    float bias0 = bias_sum[0 * F + j];
    float bias1 = bias_sum[1 * F + j];
    float bias2 = bias_sum[2 * F + j];
    float bias3 = bias_sum[3 * F + j];
    float cj = c_in[(size_t)b * F + j];

    if (tid < F) ((__half*)hbuf[0])[tid] = __float2half(h_in[(size_t)b * F + tid]);
    __syncthreads();

    int cur = 0;
    for (int t = 1; t < S; ++t) {
        float a0 = 0.f, a1 = 0.f, a2 = 0.f, a3 = 0.f;
        #pragma unroll
        for (int i = 0; i < 16; ++i) {
            uint4 hv = hbuf[cur][q * 16 + i];
            uint4 w0 = wr[i];
            uint4 w1 = wr[16 + i];
            uint4 w2 = wr[32 + i];
            uint4 w3 = lds_wo[i][tid];
            a0 = fdot2u(w0.x, hv.x, a0); a0 = fdot2u(w0.y, hv.y, a0);
            a0 = fdot2u(w0.z, hv.z, a0); a0 = fdot2u(w0.w, hv.w, a0);
            a1 = fdot2u(w1.x, hv.x, a1); a1 = fdot2u(w1.y, hv.y, a1);
            a1 = fdot2u(w1.z, hv.z, a1); a1 = fdot2u(w1.w, hv.w, a1);
            a2 = fdot2u(w2.x, hv.x, a2); a2 = fdot2u(w2.y, hv.y, a2);
            a2 = fdot2u(w2.z, hv.z, a2); a2 = fdot2u(w2.w, hv.w, a2);
            a3 = fdot2u(w3.x, hv.x, a3); a3 = fdot2u(w3.y, hv.y, a3);
            a3 = fdot2u(w3.z, hv.z, a3); a3 = fdot2u(w3.w, hv.w, a3);
        }
        // sum the 2 k-halves (lane pairs); both lanes get full sums
        a0 = dpp_add<0xB1>(a0) + bias0;
        a1 = dpp_add<0xB1>(a1) + bias1;
        a2 = dpp_add<0xB1>(a2) + bias2;
        a3 = dpp_add<0xB1>(a3) + bias3;
        float c2 = sigf(a1) * cj + sigf(a0) * tanhf_fast(a2);
        float h2 = sigf(a3) * tanhf_fast(c2);
        cj = c2;
        if (q == 0) {
            ((__half*)hbuf[cur ^ 1])[j] = __float2half(h2);
        } else {
            __builtin_nontemporal_store(h2, &out[((size_t)t * B + b) * F + j]);
        }
        __syncthreads();
        cur ^= 1;
    }
}

extern "C" void kernel_launch(void* const* d_in, const int* in_sizes, int n_in,
                              void* d_out, int out_size, void* d_ws, size_t ws_size,
                              hipStream_t stream) {
    const float* x   = (const float*)d_in[0];
    const float* lf  = (const float*)d_in[1];
    const float* Wi  = (const float*)d_in[2];
    const float* bi  = (const float*)d_in[3];
    const float* Wih = (const float*)d_in[4];
    const float* Whh = (const float*)d_in[5];
    const float* bih = (const float*)d_in[6];
    const float* bhh = (const float*)d_in[7];
    // d_in[8], d_in[9] (Wo, bo): computed-and-discarded in the reference; unused.
    float* out = (float*)d_out;

    float* ws    = (float*)d_ws;
    float* h     = ws;               // 65536 floats
    float* c     = ws + 65536;       // 65536 floats
    float* bias  = ws + 131072;      // 1024 floats
    uint4* Wpk   = (uint4*)(ws + 132096);  // 64*512 x 16B = 512 KB

    prep_kernel<<<128, 256, 0, stream>>>(Wih, Whh, bih, bhh, Wpk, bias);
    init_kernel<<<B, F, 0, stream>>>(x, Wi, bi, h, c);
    step0_kernel<<<B, 1024, 0, stream>>>(lf, Wih, Whh, bias, h, c, out);
    lstm_main<<<B, 512, 0, stream>>>(Wpk, bias, h, c, out);
}

// Round 6
// 899.684 us; speedup vs baseline: 10.4755x; 1.0179x over previous
//
#include <hip/hip_runtime.h>
#include <hip/hip_bf16.h>
#include <hip/hip_fp16.h>

#define B 256
#define L 128
#define F 256
#define S 512
#define G4 1024  // 4*F gate rows

typedef _Float16 h2raw __attribute__((ext_vector_type(2)));

__device__ __forceinline__ float fdot2u(unsigned a, unsigned b, float c) {
#if __has_builtin(__builtin_amdgcn_fdot2)
    return __builtin_amdgcn_fdot2(__builtin_bit_cast(h2raw, a), __builtin_bit_cast(h2raw, b), c, false);
#else
    __half2 ah = __builtin_bit_cast(__half2, a), bh = __builtin_bit_cast(__half2, b);
    float2 af = __half22float2(ah), bf = __half22float2(bh);
    return c + af.x * bf.x + af.y * bf.y;
#endif
}

__device__ __forceinline__ void sched_fence() {
#if __has_builtin(__builtin_amdgcn_sched_barrier)
    __builtin_amdgcn_sched_barrier(0);
#endif
}

// fast device transcendentals: v_exp_f32 / v_rcp_f32 based
__device__ __forceinline__ float fast_rcp(float x) { return __builtin_amdgcn_rcpf(x); }
__device__ __forceinline__ float sigf(float x) {
    float e = __expf(-x);
    return fast_rcp(1.0f + e);
}
__device__ __forceinline__ float tanhf_fast(float x) {
    x = fminf(fmaxf(x, -15.0f), 15.0f);
    float e = __expf(-2.0f * x);
    return (1.0f - e) * fast_rcp(1.0f + e);
}

template <int CTRL>
__device__ __forceinline__ float dpp_add(float x) {
    int v = __builtin_amdgcn_update_dpp(0, __builtin_bit_cast(int, x), CTRL, 0xF, 0xF, true);
    return x + __builtin_bit_cast(float, v);
}

// Prep: pack combined W = W_ih + W_hh for the 512-thread main kernel.
// Thread tid: j = tid>>1 (hidden unit), q = tid&1 (k-half).
// Chunk n in [0,64): n<48 -> register gates g=n>>4 (i,f,g), m=n&15;
//                    n>=48 -> LDS gate g=3 (o), m=n-48.
// Wpk[n*512+tid] = 4 half2 = k-pairs kp = q*64 + m*4 + {0..3} of row g*256+j.
__global__ void prep_kernel(const float* __restrict__ Wih,
                            const float* __restrict__ Whh,
                            const float* __restrict__ bih,
                            const float* __restrict__ bhh,
                            uint4* __restrict__ Wpk, float* __restrict__ bias_sum) {
    int e = blockIdx.x * blockDim.x + threadIdx.x;  // 32768 elements
    if (e < G4) bias_sum[e] = bih[e] + bhh[e];
    int n = e >> 9, tid = e & 511;
    int j = tid >> 1, q = tid & 1;
    int g = (n < 48) ? (n >> 4) : 3;
    int m = (n < 48) ? (n & 15) : (n - 48);
    int r = g * F + j;
    int kp0 = q * 64 + m * 4;
    unsigned pk[4];
    #pragma unroll
    for (int i = 0; i < 4; ++i) {
        int k = 2 * (kp0 + i);
        float w0 = Wih[(size_t)r * F + k]     + Whh[(size_t)r * F + k];
        float w1 = Wih[(size_t)r * F + k + 1] + Whh[(size_t)r * F + k + 1];
        pk[i] = __builtin_bit_cast(unsigned, __floats2half2_rn(w0, w1));
    }
    Wpk[(size_t)n * 512 + tid] = make_uint4(pk[0], pk[1], pk[2], pk[3]);
}

// init = elu(x[0] @ Wi.T + bi) -> h0, c0 (fp32 in workspace), float4 loads
__global__ void init_kernel(const float* __restrict__ x,
                            const float* __restrict__ Wi,
                            const float* __restrict__ bi,
                            float* __restrict__ h, float* __restrict__ c) {
    __shared__ float4 xs4[L / 4];
    int b = blockIdx.x, j = threadIdx.x;
    if (j < L / 4) xs4[j] = ((const float4*)(x + (size_t)b * L))[j];
    __syncthreads();
    float acc = bi[j];
    const float4* wp = (const float4*)(Wi + (size_t)j * L);
    #pragma unroll 8
    for (int k = 0; k < L / 4; ++k) {
        float4 w = wp[k], xv = xs4[k];
        acc += w.x * xv.x + w.y * xv.y + w.z * xv.z + w.w * xv.w;
    }
    float v = acc > 0.0f ? acc : expm1f(acc);
    h[b * F + j] = v;
    c[b * F + j] = v;
}

// Step 0: gates = last_feat @ W_ih.T + h0 @ W_hh.T + bias.
// 1024 threads: j = tid&255, q = tid>>8 picks a 128-wide slice of the
// concatenated K=512 ([inp;h0]) dimension. float4 loads, LDS partial reduce.
__global__ void step0_kernel(const float* __restrict__ lf,
                             const float* __restrict__ Wih,
                             const float* __restrict__ Whh,
                             const float* __restrict__ bias_sum,
                             float* __restrict__ h, float* __restrict__ c,
                             float* __restrict__ out) {
    __shared__ float vecs[2 * F];            // [inp(256) ; h0(256)]
    __shared__ float partial[3][4][F];
    int b = blockIdx.x, tid = threadIdx.x;
    int j = tid & (F - 1), q = tid >> 8;
    if (q == 0) vecs[j] = lf[(size_t)b * F + j];
    else if (q == 1) vecs[F + j] = h[(size_t)b * F + j];
    __syncthreads();
    const float* mat = (q < 2) ? Wih : Whh;
    int ks = (q & 1) * 128;
    const float4* vp = (const float4*)(&vecs[(q >> 1) * F + ks]);
    float a[4] = {0.f, 0.f, 0.f, 0.f};
    #pragma unroll
    for (int g = 0; g < 4; ++g) {
        const float4* wp = (const float4*)(&mat[(size_t)(g * F + j) * F + ks]);
        float acc = 0.f;
        #pragma unroll 8
        for (int i = 0; i < 32; ++i) {
            float4 w = wp[i], v = vp[i];
            acc += w.x * v.x + w.y * v.y + w.z * v.z + w.w * v.w;
        }
        a[g] = acc;
    }
    if (q > 0) {
        #pragma unroll
        for (int g = 0; g < 4; ++g) partial[q - 1][g][j] = a[g];
    }
    __syncthreads();
    if (q == 0) {
        #pragma unroll
        for (int g = 0; g < 4; ++g) {
            for (int p = 0; p < 3; ++p) a[g] += partial[p][g][j];
            a[g] += bias_sum[g * F + j];
        }
        float c0v = c[(size_t)b * F + j];
        float c1v = sigf(a[1]) * c0v + sigf(a[0]) * tanhf_fast(a[2]);
        float h1v = sigf(a[3]) * tanhf_fast(c1v);
        h[(size_t)b * F + j] = h1v;
        c[(size_t)b * F + j] = c1v;
        out[(size_t)b * F + j] = h1v;  // t=0 row
    }
}

// Main recurrence. One block of 512 threads per batch element.
// j = tid>>1 (hidden unit), q = tid&1 (k-half, reduced via DPP xor-1).
// Weights: gates i,f,g register-resident (192 dwords/thread); gate o in LDS.
// K-loop runs in 8 chunks of 2 with 1-chunk prefetch + sched fences so peak
// liveness stays ~243 <= 256 regs -> no AGPR shuttle (R5's 2.2x VALU surplus).
__launch_bounds__(512, 2)
__global__ void lstm_main(const uint4* __restrict__ Wpk,
                          const float* __restrict__ bias_sum,
                          const float* __restrict__ h_in,
                          const float* __restrict__ c_in,
                          float* __restrict__ out) {
    int b = blockIdx.x;
    int tid = threadIdx.x;
    int j = tid >> 1;
    int q = tid & 1;

    __shared__ uint4 lds_wo[16][512];   // gate-o weights, 128 KB
    __shared__ uint4 hbuf[2][F / 8];    // 2 x 512 B hidden state (f16)

    // One-time: gates i,f,g into registers (coalesced), gate o into LDS.
    uint4 wr[48];
    #pragma unroll
    for (int n = 0; n < 48; ++n) wr[n] = Wpk[(size_t)n * 512 + tid];
    #pragma unroll
    for (int m = 0; m < 16; ++m) lds_wo[m][tid] = Wpk[(size_t)(48 + m) * 512 + tid];

    float bias0 = bias_sum[0 * F + j];
    float bias1 = bias_sum[1 * F + j];
    float bias2 = bias_sum[2 * F + j];
    float bias3 = bias_sum[3 * F + j];
    float cj = c_in[(size_t)b * F + j];

    if (tid < F) ((__half*)hbuf[0])[tid] = __float2half(h_in[(size_t)b * F + tid]);
    __syncthreads();

    int cur = 0;
    for (int t = 1; t < S; ++t) {
        const uint4* hb = hbuf[cur] + q * 16;
        float a0 = 0.f, a1 = 0.f, a2 = 0.f, a3 = 0.f;

        uint4 hvA0 = hb[0], hvA1 = hb[1];
        uint4 woA0 = lds_wo[0][tid], woA1 = lds_wo[1][tid];
        #pragma unroll
        for (int c = 0; c < 8; ++c) {
            uint4 hvB0, hvB1, woB0, woB1;
            if (c < 7) {
                hvB0 = hb[2 * c + 2];
                hvB1 = hb[2 * c + 3];
                woB0 = lds_wo[2 * c + 2][tid];
                woB1 = lds_wo[2 * c + 3][tid];
            }
            #pragma unroll
            for (int u = 0; u < 2; ++u) {
                const int i = 2 * c + u;
                uint4 hv = (u == 0) ? hvA0 : hvA1;
                uint4 w3 = (u == 0) ? woA0 : woA1;
                uint4 w0 = wr[i];
                uint4 w1 = wr[16 + i];
                uint4 w2 = wr[32 + i];
                a0 = fdot2u(w0.x, hv.x, a0); a0 = fdot2u(w0.y, hv.y, a0);
                a0 = fdot2u(w0.z, hv.z, a0); a0 = fdot2u(w0.w, hv.w, a0);
                a1 = fdot2u(w1.x, hv.x, a1); a1 = fdot2u(w1.y, hv.y, a1);
                a1 = fdot2u(w1.z, hv.z, a1); a1 = fdot2u(w1.w, hv.w, a1);
                a2 = fdot2u(w2.x, hv.x, a2); a2 = fdot2u(w2.y, hv.y, a2);
                a2 = fdot2u(w2.z, hv.z, a2); a2 = fdot2u(w2.w, hv.w, a2);
                a3 = fdot2u(w3.x, hv.x, a3); a3 = fdot2u(w3.y, hv.y, a3);
                a3 = fdot2u(w3.z, hv.z, a3); a3 = fdot2u(w3.w, hv.w, a3);
            }
            hvA0 = hvB0; hvA1 = hvB1; woA0 = woB0; woA1 = woB1;
            sched_fence();  // keep chunk c+1's loads from hoisting further up
        }

        // sum the 2 k-halves (lane pairs); both lanes get full sums
        a0 = dpp_add<0xB1>(a0) + bias0;
        a1 = dpp_add<0xB1>(a1) + bias1;
        a2 = dpp_add<0xB1>(a2) + bias2;
        a3 = dpp_add<0xB1>(a3) + bias3;
        float c2 = sigf(a1) * cj + sigf(a0) * tanhf_fast(a2);
        float h2 = sigf(a3) * tanhf_fast(c2);
        cj = c2;
        if (q == 0) {
            ((__half*)hbuf[cur ^ 1])[j] = __float2half(h2);
        } else {
            __builtin_nontemporal_store(h2, &out[((size_t)t * B + b) * F + j]);
        }
        __syncthreads();
        cur ^= 1;
    }
}

extern "C" void kernel_launch(void* const* d_in, const int* in_sizes, int n_in,
                              void* d_out, int out_size, void* d_ws, size_t ws_size,
                              hipStream_t stream) {
    const float* x   = (const float*)d_in[0];
    const float* lf  = (const float*)d_in[1];
    const float* Wi  = (const float*)d_in[2];
    const float* bi  = (const float*)d_in[3];
    const float* Wih = (const float*)d_in[4];
    const float* Whh = (const float*)d_in[5];
    const float* bih = (const float*)d_in[6];
    const float* bhh = (const float*)d_in[7];
    // d_in[8], d_in[9] (Wo, bo): computed-and-discarded in the reference; unused.
    float* out = (float*)d_out;

    float* ws    = (float*)d_ws;
    float* h     = ws;               // 65536 floats
    float* c     = ws + 65536;       // 65536 floats
    float* bias  = ws + 131072;      // 1024 floats
    uint4* Wpk   = (uint4*)(ws + 132096);  // 64*512 x 16B = 512 KB

    prep_kernel<<<128, 256, 0, stream>>>(Wih, Whh, bih, bhh, Wpk, bias);
    init_kernel<<<B, F, 0, stream>>>(x, Wi, bi, h, c);
    step0_kernel<<<B, 1024, 0, stream>>>(lf, Wih, Whh, bias, h, c, out);
    lstm_main<<<B, 512, 0, stream>>>(Wpk, bias, h, c, out);
}